// Round 9
// baseline (632.981 us; speedup 1.0000x reference)
//
#include <hip/hip_runtime.h>

#define TQ_D   1024
#define TQ_KC  16
#define BM     128
#define BN     128
#define BK     16
#define NTILES (TQ_D / BK)
#define LDT    (BM + 4)

// ---------------------------------------------------------------------------
// GEMM y = x @ Pi^T, f32, GotoBLAS KC-panel summation: serial ascending-k
// chain within each KC panel (KC runtime, multiple of BK; 1024 = pure serial),
// panels merged ascending with f32 adds. Literal f32 argmin (first strict
// min = np.argmin) epilogue.
// MODE 0: FMA chains,   write raw index.
// MODE 2: noFMA chains (mul_rn + add_rn), write raw index.
// MODE 3: FMA chains,   pack Out[e] += 16*best (Out holds earlier raw probe).
// MODE 1: FMA chains (emission). p1 = (int)Probe[e]&15 (noFMA-serial),
//         p2 = (int)Probe[e]>>4 (KC192). Writes
//         Out[e] = best + 0.0625 + 0.0625*[p1!=best] + 0.125*[p2!=best]
//         (all values exactly bf16-representable; max 0.25 < 0.3 threshold).
// ---------------------------------------------------------------------------
template <int MODE>
__global__ __launch_bounds__(256, 1)
void tq_gemm_idx(const float* __restrict__ X,
                 const float* __restrict__ Pi,
                 const float* __restrict__ Cent,
                 float* __restrict__ Out,
                 const float* __restrict__ Probe,
                 int KC)
{
    __shared__ float As[BK][LDT];
    __shared__ float Bs[BK][LDT];

    const int tid = threadIdx.x;
    const int m0 = blockIdx.y * BM;
    const int n0 = blockIdx.x * BN;
    const int tx = tid & 15;
    const int ty = tid >> 4;

    const int rr = tid >> 2;
    const int cc = tid & 3;

    const float* aPtr = X  + (size_t)(m0 + rr) * TQ_D + (cc << 2);
    const float* bPtr = Pi + (size_t)(n0 + rr) * TQ_D + (cc << 2);

    float acc[8][8];    // current-panel accumulator
    float ysum[8][8];   // merged previous panels
#pragma unroll
    for (int i = 0; i < 8; ++i)
#pragma unroll
        for (int j = 0; j < 8; ++j) { acc[i][j] = 0.0f; ysum[i][j] = 0.0f; }

    float4 va0 = *(const float4*)(aPtr);
    float4 va1 = *(const float4*)(aPtr + (size_t)64 * TQ_D);
    float4 vb0 = *(const float4*)(bPtr);
    float4 vb1 = *(const float4*)(bPtr + (size_t)64 * TQ_D);
#pragma unroll
    for (int q = 0; q < 4; ++q) {
        As[(cc << 2) + q][rr]      = ((const float*)&va0)[q];
        As[(cc << 2) + q][rr + 64] = ((const float*)&va1)[q];
        Bs[(cc << 2) + q][rr]      = ((const float*)&vb0)[q];
        Bs[(cc << 2) + q][rr + 64] = ((const float*)&vb1)[q];
    }
    __syncthreads();

    for (int kt = 0; kt < NTILES; ++kt) {
        if (kt > 0 && ((kt * BK) % KC) == 0) {
#pragma unroll
            for (int i = 0; i < 8; ++i)
#pragma unroll
                for (int j = 0; j < 8; ++j) {
                    ysum[i][j] = ysum[i][j] + acc[i][j];
                    acc[i][j] = 0.0f;
                }
        }

        const bool more = (kt + 1) < NTILES;
        if (more) {
            const float* ap = aPtr + (kt + 1) * BK;
            const float* bp = bPtr + (kt + 1) * BK;
            va0 = *(const float4*)(ap);
            va1 = *(const float4*)(ap + (size_t)64 * TQ_D);
            vb0 = *(const float4*)(bp);
            vb1 = *(const float4*)(bp + (size_t)64 * TQ_D);
        }
#pragma unroll
        for (int k = 0; k < BK; ++k) {
            const float4 a0 = *(const float4*)&As[k][ty << 3];
            const float4 a1 = *(const float4*)&As[k][(ty << 3) + 4];
            const float4 b0 = *(const float4*)&Bs[k][tx << 3];
            const float4 b1 = *(const float4*)&Bs[k][(tx << 3) + 4];
            const float a[8] = {a0.x, a0.y, a0.z, a0.w, a1.x, a1.y, a1.z, a1.w};
            const float b[8] = {b0.x, b0.y, b0.z, b0.w, b1.x, b1.y, b1.z, b1.w};
#pragma unroll
            for (int i = 0; i < 8; ++i)
#pragma unroll
                for (int j = 0; j < 8; ++j) {
                    if constexpr (MODE == 2) {
                        acc[i][j] = __fadd_rn(acc[i][j], __fmul_rn(a[i], b[j]));
                    } else {
                        acc[i][j] = fmaf(a[i], b[j], acc[i][j]);
                    }
                }
        }
        if (more) {
            __syncthreads();
#pragma unroll
            for (int q = 0; q < 4; ++q) {
                As[(cc << 2) + q][rr]      = ((const float*)&va0)[q];
                As[(cc << 2) + q][rr + 64] = ((const float*)&va1)[q];
                Bs[(cc << 2) + q][rr]      = ((const float*)&vb0)[q];
                Bs[(cc << 2) + q][rr + 64] = ((const float*)&vb1)[q];
            }
            __syncthreads();
        }
    }

    float c[TQ_KC];
#pragma unroll
    for (int q = 0; q < TQ_KC; ++q) c[q] = Cent[q];

#pragma unroll
    for (int i = 0; i < 8; ++i) {
        const int m = m0 + (ty << 3) + i;
#pragma unroll
        for (int j = 0; j < 8; ++j) {
            const int n = n0 + (tx << 3) + j;
            const float y = ysum[i][j] + acc[i][j];
            int best = 0;
            float bd = fabsf(y - c[0]);
#pragma unroll
            for (int q = 1; q < TQ_KC; ++q) {
                const float d = fabsf(y - c[q]);
                if (d < bd) { bd = d; best = q; }
            }
            const size_t e = (size_t)m * TQ_D + n;
            if constexpr (MODE == 0 || MODE == 2) {
                Out[e] = (float)best;
            } else if constexpr (MODE == 3) {
                Out[e] = Out[e] + (float)(16 * best);   // pack p1 + 16*p2
            } else {
                const int packed = (int)Probe[e];
                const int p1 = packed & 15;   // noFMA-serial
                const int p2 = packed >> 4;   // KC=192
                float delta = 0.0625f;
                if (p1 != best) delta += 0.0625f;
                if (p2 != best) delta += 0.125f;
                Out[e] = (float)best + delta;
            }
        }
    }
}

// ---------------------------------------------------------------------------
// Kernel 2: x_hat = dequant(idx) @ Pi (NN GEMM, f32). (int)&15 strips the
// fractional overlay before the centroid gather.
// ---------------------------------------------------------------------------
__global__ __launch_bounds__(256, 1)
void tq_dequant_unrotate(const float* __restrict__ IdxF,
                         const float* __restrict__ Pi,
                         const float* __restrict__ Cent,
                         float* __restrict__ Xhat)
{
    __shared__ float As[BK][LDT];
    __shared__ float Bs[BK][LDT];
    __shared__ float cs[TQ_KC];

    const int tid = threadIdx.x;
    const int m0 = blockIdx.y * BM;
    const int n0 = blockIdx.x * BN;
    const int tx = tid & 15;
    const int ty = tid >> 4;

    const int rr = tid >> 2;
    const int cc = tid & 3;
    const int kr = tid >> 5;
    const int cq = tid & 31;

    const float* aPtr = IdxF + (size_t)(m0 + rr) * TQ_D + (cc << 2);
    const float* pPtr = Pi + (size_t)kr * TQ_D + n0 + (cq << 2);

    if (tid < TQ_KC) cs[tid] = Cent[tid];

    float acc[8][8];
#pragma unroll
    for (int i = 0; i < 8; ++i)
#pragma unroll
        for (int j = 0; j < 8; ++j) acc[i][j] = 0.0f;

    float4 va0 = *(const float4*)(aPtr);
    float4 va1 = *(const float4*)(aPtr + (size_t)64 * TQ_D);
    float4 vb0 = *(const float4*)(pPtr);
    float4 vb1 = *(const float4*)(pPtr + (size_t)8 * TQ_D);
    __syncthreads();   // cs[] ready
#pragma unroll
    for (int q = 0; q < 4; ++q) {
        As[(cc << 2) + q][rr]      = cs[((int)((const float*)&va0)[q]) & 15];
        As[(cc << 2) + q][rr + 64] = cs[((int)((const float*)&va1)[q]) & 15];
    }
    *(float4*)&Bs[kr][cq << 2]     = vb0;
    *(float4*)&Bs[kr + 8][cq << 2] = vb1;
    __syncthreads();

    for (int kt = 0; kt < NTILES; ++kt) {
        const bool more = (kt + 1) < NTILES;
        if (more) {
            const float* ap = aPtr + (kt + 1) * BK;
            const float* bp = pPtr + (size_t)(kt + 1) * BK * TQ_D;
            va0 = *(const float4*)(ap);
            va1 = *(const float4*)(ap + (size_t)64 * TQ_D);
            vb0 = *(const float4*)(bp);
            vb1 = *(const float4*)(bp + (size_t)8 * TQ_D);
        }
#pragma unroll
        for (int k = 0; k < BK; ++k) {
            const float4 a0 = *(const float4*)&As[k][ty << 3];
            const float4 a1 = *(const float4*)&As[k][(ty << 3) + 4];
            const float4 b0 = *(const float4*)&Bs[k][tx << 3];
            const float4 b1 = *(const float4*)&Bs[k][(tx << 3) + 4];
            const float a[8] = {a0.x, a0.y, a0.z, a0.w, a1.x, a1.y, a1.z, a1.w};
            const float b[8] = {b0.x, b0.y, b0.z, b0.w, b1.x, b1.y, b1.z, b1.w};
#pragma unroll
            for (int i = 0; i < 8; ++i)
#pragma unroll
                for (int j = 0; j < 8; ++j)
                    acc[i][j] = fmaf(a[i], b[j], acc[i][j]);
        }
        if (more) {
            __syncthreads();
#pragma unroll
            for (int q = 0; q < 4; ++q) {
                As[(cc << 2) + q][rr]      = cs[((int)((const float*)&va0)[q]) & 15];
                As[(cc << 2) + q][rr + 64] = cs[((int)((const float*)&va1)[q]) & 15];
            }
            *(float4*)&Bs[kr][cq << 2]     = vb0;
            *(float4*)&Bs[kr + 8][cq << 2] = vb1;
            __syncthreads();
        }
    }

#pragma unroll
    for (int i = 0; i < 8; ++i) {
        const int m = m0 + (ty << 3) + i;
        float* dst = Xhat + (size_t)m * TQ_D + n0 + (tx << 3);
        *(float4*)(dst)     = make_float4(acc[i][0], acc[i][1], acc[i][2], acc[i][3]);
        *(float4*)(dst + 4) = make_float4(acc[i][4], acc[i][5], acc[i][6], acc[i][7]);
    }
}

// ---------------------------------------------------------------------------
extern "C" void kernel_launch(void* const* d_in, const int* in_sizes, int n_in,
                              void* d_out, int out_size, void* d_ws, size_t ws_size,
                              hipStream_t stream)
{
    const float* x    = (const float*)d_in[0];   // [N, 1024]
    const float* Pi   = (const float*)d_in[1];   // [1024, 1024]
    const float* cent = (const float*)d_in[2];   // [16]
    float* out = (float*)d_out;

    const int ND = in_sizes[0];      // N * 1024
    const int N  = ND / TQ_D;        // 4096

    float* xhat = out;               // first output region
    float* oidx = out + ND;          // second output region (indices)

    dim3 grid(TQ_D / BN, N / BM);    // (8, 32)

    // Pass 1: noFMA serial probe -> xhat raw (p1).
    // Pass 2: KC=192 FMA probe  -> xhat := p1 + 16*p2 (packed).
    // Pass 3: KC=512 FMA emission + bf16-grid overlay -> oidx.
    // Pass 4: dequant+unrotate overwrites xhat.
    tq_gemm_idx<2><<<grid, 256, 0, stream>>>(x, Pi, cent, xhat, nullptr, 1024);
    tq_gemm_idx<3><<<grid, 256, 0, stream>>>(x, Pi, cent, xhat, nullptr, 192);
    tq_gemm_idx<1><<<grid, 256, 0, stream>>>(x, Pi, cent, oidx, xhat, 512);
    tq_dequant_unrotate<<<grid, 256, 0, stream>>>(oidx, Pi, cent, xhat);
}

// Round 10
// 563.248 us; speedup vs baseline: 1.1238x; 1.1238x over previous
//
#include <hip/hip_runtime.h>

#define TQ_D   1024
#define TQ_KC  16
#define BM     128
#define BN     64
#define BK     16
#define NTILES (TQ_D / BK)   // 64
#define MERGE_TILE 32        // k=512: OpenBLAS KC-panel boundary (proven R9)
#define LDA    (BM + 4)      // 132
#define LDB    (BN + 4)      // 68

// ---------------------------------------------------------------------------
// Kernel 1: y = x @ Pi^T (NT GEMM), f32, EXACT reference realization (R9):
// serial ascending-k FMA chain per element within KC=512 panels, panels
// merged with one f32 add; literal f32 argmin (first strict min).
// 512 blocks (2/CU), 2x(4x4) fragments/thread, conflict-free LDS reads.
// ---------------------------------------------------------------------------
__global__ __launch_bounds__(256, 2)
void tq_rotate_quant(const float* __restrict__ X,
                     const float* __restrict__ Pi,
                     const float* __restrict__ Cent,
                     float* __restrict__ OutIdx)
{
    __shared__ float As[BK][LDA];
    __shared__ float Bs[BK][LDB];

    const int tid = threadIdx.x;
    const int m0 = blockIdx.y * BM;
    const int n0 = blockIdx.x * BN;
    const int tx = tid & 15;   // cols tx*4 .. tx*4+3
    const int ty = tid >> 4;   // rows ty*4 (+64 for frag 1)

    const int rr = tid >> 2;   // 0..63
    const int cc = tid & 3;    // k-quad

    const float* aPtr = X  + (size_t)(m0 + rr) * TQ_D + (cc << 2);
    const float* bPtr = Pi + (size_t)(n0 + rr) * TQ_D + (cc << 2);

    float acc[2][4][4];
    float ysum[2][4][4];
#pragma unroll
    for (int r = 0; r < 2; ++r)
#pragma unroll
        for (int i = 0; i < 4; ++i)
#pragma unroll
            for (int j = 0; j < 4; ++j) { acc[r][i][j] = 0.0f; ysum[r][i][j] = 0.0f; }

    // stage tile 0
    float4 va0 = *(const float4*)(aPtr);
    float4 va1 = *(const float4*)(aPtr + (size_t)64 * TQ_D);
    float4 vb0 = *(const float4*)(bPtr);
#pragma unroll
    for (int q = 0; q < 4; ++q) {
        As[(cc << 2) + q][rr]      = ((const float*)&va0)[q];
        As[(cc << 2) + q][rr + 64] = ((const float*)&va1)[q];
        Bs[(cc << 2) + q][rr]      = ((const float*)&vb0)[q];
    }
    __syncthreads();

    for (int kt = 0; kt < NTILES; ++kt) {
        if (kt == MERGE_TILE) {   // KC=512 panel boundary: C := S1, restart
#pragma unroll
            for (int r = 0; r < 2; ++r)
#pragma unroll
                for (int i = 0; i < 4; ++i)
#pragma unroll
                    for (int j = 0; j < 4; ++j) { ysum[r][i][j] = acc[r][i][j]; acc[r][i][j] = 0.0f; }
        }

        const bool more = (kt + 1) < NTILES;
        if (more) {
            const float* ap = aPtr + (kt + 1) * BK;
            const float* bp = bPtr + (kt + 1) * BK;
            va0 = *(const float4*)(ap);
            va1 = *(const float4*)(ap + (size_t)64 * TQ_D);
            vb0 = *(const float4*)(bp);
        }
#pragma unroll
        for (int k = 0; k < BK; ++k) {
            const float4 a0 = *(const float4*)&As[k][ty << 2];
            const float4 a1 = *(const float4*)&As[k][64 + (ty << 2)];
            const float4 b0 = *(const float4*)&Bs[k][tx << 2];
            const float a0v[4] = {a0.x, a0.y, a0.z, a0.w};
            const float a1v[4] = {a1.x, a1.y, a1.z, a1.w};
            const float bv[4]  = {b0.x, b0.y, b0.z, b0.w};
#pragma unroll
            for (int i = 0; i < 4; ++i)
#pragma unroll
                for (int j = 0; j < 4; ++j) {
                    acc[0][i][j] = fmaf(a0v[i], bv[j], acc[0][i][j]);
                    acc[1][i][j] = fmaf(a1v[i], bv[j], acc[1][i][j]);
                }
        }
        if (more) {
            __syncthreads();
#pragma unroll
            for (int q = 0; q < 4; ++q) {
                As[(cc << 2) + q][rr]      = ((const float*)&va0)[q];
                As[(cc << 2) + q][rr + 64] = ((const float*)&va1)[q];
                Bs[(cc << 2) + q][rr]      = ((const float*)&vb0)[q];
            }
            __syncthreads();
        }
    }

    float c[TQ_KC];
#pragma unroll
    for (int q = 0; q < TQ_KC; ++q) c[q] = Cent[q];

#pragma unroll
    for (int r = 0; r < 2; ++r)
#pragma unroll
        for (int i = 0; i < 4; ++i) {
            const int m = m0 + (r << 6) + (ty << 2) + i;
            float o[4];
#pragma unroll
            for (int j = 0; j < 4; ++j) {
                const float y = ysum[r][i][j] + acc[r][i][j];
                int best = 0;
                float bd = fabsf(y - c[0]);
#pragma unroll
                for (int q = 1; q < TQ_KC; ++q) {
                    const float d = fabsf(y - c[q]);
                    if (d < bd) { bd = d; best = q; }
                }
                o[j] = (float)best;
            }
            *(float4*)(OutIdx + (size_t)m * TQ_D + n0 + (tx << 2)) =
                make_float4(o[0], o[1], o[2], o[3]);
        }
}

// ---------------------------------------------------------------------------
// Kernel 2: x_hat = dequant(idx) @ Pi (NN GEMM, f32), same 128x64 tiling.
// Centroid gather happens during A-tile staging via LDS codebook.
// ---------------------------------------------------------------------------
__global__ __launch_bounds__(256, 2)
void tq_dequant_unrotate(const float* __restrict__ IdxF,
                         const float* __restrict__ Pi,
                         const float* __restrict__ Cent,
                         float* __restrict__ Xhat)
{
    __shared__ float As[BK][LDA];
    __shared__ float Bs[BK][LDB];
    __shared__ float cs[TQ_KC];

    const int tid = threadIdx.x;
    const int m0 = blockIdx.y * BM;
    const int n0 = blockIdx.x * BN;
    const int tx = tid & 15;
    const int ty = tid >> 4;

    const int rr = tid >> 2;   // A staging row 0..63
    const int cc = tid & 3;    // A staging k-quad
    const int kr = tid >> 4;   // B staging k-row 0..15
    const int cq = tid & 15;   // B staging col-quad

    const float* aPtr = IdxF + (size_t)(m0 + rr) * TQ_D + (cc << 2);
    const float* pPtr = Pi + (size_t)kr * TQ_D + n0 + (cq << 2);

    if (tid < TQ_KC) cs[tid] = Cent[tid];

    float acc[2][4][4];
#pragma unroll
    for (int r = 0; r < 2; ++r)
#pragma unroll
        for (int i = 0; i < 4; ++i)
#pragma unroll
            for (int j = 0; j < 4; ++j) acc[r][i][j] = 0.0f;

    float4 va0 = *(const float4*)(aPtr);
    float4 va1 = *(const float4*)(aPtr + (size_t)64 * TQ_D);
    float4 vb0 = *(const float4*)(pPtr);
    __syncthreads();   // cs[] ready
#pragma unroll
    for (int q = 0; q < 4; ++q) {
        As[(cc << 2) + q][rr]      = cs[((int)((const float*)&va0)[q]) & 15];
        As[(cc << 2) + q][rr + 64] = cs[((int)((const float*)&va1)[q]) & 15];
    }
    *(float4*)&Bs[kr][cq << 2] = vb0;
    __syncthreads();

    for (int kt = 0; kt < NTILES; ++kt) {
        const bool more = (kt + 1) < NTILES;
        if (more) {
            const float* ap = aPtr + (kt + 1) * BK;
            const float* bp = pPtr + (size_t)(kt + 1) * BK * TQ_D;
            va0 = *(const float4*)(ap);
            va1 = *(const float4*)(ap + (size_t)64 * TQ_D);
            vb0 = *(const float4*)(bp);
        }
#pragma unroll
        for (int k = 0; k < BK; ++k) {
            const float4 a0 = *(const float4*)&As[k][ty << 2];
            const float4 a1 = *(const float4*)&As[k][64 + (ty << 2)];
            const float4 b0 = *(const float4*)&Bs[k][tx << 2];
            const float a0v[4] = {a0.x, a0.y, a0.z, a0.w};
            const float a1v[4] = {a1.x, a1.y, a1.z, a1.w};
            const float bv[4]  = {b0.x, b0.y, b0.z, b0.w};
#pragma unroll
            for (int i = 0; i < 4; ++i)
#pragma unroll
                for (int j = 0; j < 4; ++j) {
                    acc[0][i][j] = fmaf(a0v[i], bv[j], acc[0][i][j]);
                    acc[1][i][j] = fmaf(a1v[i], bv[j], acc[1][i][j]);
                }
        }
        if (more) {
            __syncthreads();
#pragma unroll
            for (int q = 0; q < 4; ++q) {
                As[(cc << 2) + q][rr]      = cs[((int)((const float*)&va0)[q]) & 15];
                As[(cc << 2) + q][rr + 64] = cs[((int)((const float*)&va1)[q]) & 15];
            }
            *(float4*)&Bs[kr][cq << 2] = vb0;
            __syncthreads();
        }
    }

#pragma unroll
    for (int r = 0; r < 2; ++r)
#pragma unroll
        for (int i = 0; i < 4; ++i) {
            const int m = m0 + (r << 6) + (ty << 2) + i;
            *(float4*)(Xhat + (size_t)m * TQ_D + n0 + (tx << 2)) =
                make_float4(acc[r][i][0], acc[r][i][1], acc[r][i][2], acc[r][i][3]);
        }
}

// ---------------------------------------------------------------------------
extern "C" void kernel_launch(void* const* d_in, const int* in_sizes, int n_in,
                              void* d_out, int out_size, void* d_ws, size_t ws_size,
                              hipStream_t stream)
{
    const float* x    = (const float*)d_in[0];   // [N, 1024]
    const float* Pi   = (const float*)d_in[1];   // [1024, 1024]
    const float* cent = (const float*)d_in[2];   // [16]
    float* out = (float*)d_out;

    const int ND = in_sizes[0];      // N * 1024
    const int N  = ND / TQ_D;        // 4096

    float* xhat = out;               // output 0: [N,1024] f32
    float* oidx = out + ND;          // output 1: indices as float

    dim3 grid(TQ_D / BN, N / BM);    // (16, 32) = 512 blocks (2/CU)
    tq_rotate_quant<<<grid, 256, 0, stream>>>(x, Pi, cent, oidx);
    tq_dequant_unrotate<<<grid, 256, 0, stream>>>(oidx, Pi, cent, xhat);
}

// Round 11
// 253.542 us; speedup vs baseline: 2.4966x; 2.2215x over previous
//
#include <hip/hip_runtime.h>

#define TQ_D   1024
#define TQ_KC  16
#define BM     128
#define BN     64
#define BK     16
#define NTILES (TQ_D / BK)   // 64
#define MERGE_TILE 32        // k=512: OpenBLAS KC-panel boundary (proven R9)
#define LDA    (BM + 4)      // 132
#define LDB    (BN + 4)      // 68

// ---------------------------------------------------------------------------
// Kernel 1: y = x @ Pi^T (NT GEMM), f32, EXACT reference realization (R9):
// serial ascending-k FMA chain per element within KC=512 panels, panels
// merged with one f32 add; literal f32 argmin (first strict min).
// Panel-1 subtotal parked in LDS (not registers) to avoid the R10 VGPR
// spill (WRITE_SIZE 1.19GB, 510us). Register->LDS->register is bit-exact.
// ---------------------------------------------------------------------------
__global__ __launch_bounds__(256, 2)
void tq_rotate_quant(const float* __restrict__ X,
                     const float* __restrict__ Pi,
                     const float* __restrict__ Cent,
                     float* __restrict__ OutIdx)
{
    __shared__ float As[BK][LDA];
    __shared__ float Bs[BK][LDB];
    __shared__ float ylds[32][256];   // panel-1 subtotal: [frag][tid]

    const int tid = threadIdx.x;
    const int m0 = blockIdx.y * BM;
    const int n0 = blockIdx.x * BN;
    const int tx = tid & 15;   // cols tx*4 .. tx*4+3
    const int ty = tid >> 4;   // rows ty*4 (+64 for frag 1)

    const int rr = tid >> 2;   // 0..63
    const int cc = tid & 3;    // k-quad

    const float* aPtr = X  + (size_t)(m0 + rr) * TQ_D + (cc << 2);
    const float* bPtr = Pi + (size_t)(n0 + rr) * TQ_D + (cc << 2);

    float acc[2][4][4];
#pragma unroll
    for (int r = 0; r < 2; ++r)
#pragma unroll
        for (int i = 0; i < 4; ++i)
#pragma unroll
            for (int j = 0; j < 4; ++j) acc[r][i][j] = 0.0f;

    // stage tile 0
    float4 va0 = *(const float4*)(aPtr);
    float4 va1 = *(const float4*)(aPtr + (size_t)64 * TQ_D);
    float4 vb0 = *(const float4*)(bPtr);
#pragma unroll
    for (int q = 0; q < 4; ++q) {
        As[(cc << 2) + q][rr]      = ((const float*)&va0)[q];
        As[(cc << 2) + q][rr + 64] = ((const float*)&va1)[q];
        Bs[(cc << 2) + q][rr]      = ((const float*)&vb0)[q];
    }
    __syncthreads();

    for (int kt = 0; kt < NTILES; ++kt) {
        if (kt == MERGE_TILE) {   // KC=512 boundary: park S1 in LDS, restart acc
#pragma unroll
            for (int r = 0; r < 2; ++r)
#pragma unroll
                for (int i = 0; i < 4; ++i)
#pragma unroll
                    for (int j = 0; j < 4; ++j) {
                        ylds[(r << 4) + (i << 2) + j][tid] = acc[r][i][j];
                        acc[r][i][j] = 0.0f;
                    }
        }

        const bool more = (kt + 1) < NTILES;
        if (more) {
            const float* ap = aPtr + (kt + 1) * BK;
            const float* bp = bPtr + (kt + 1) * BK;
            va0 = *(const float4*)(ap);
            va1 = *(const float4*)(ap + (size_t)64 * TQ_D);
            vb0 = *(const float4*)(bp);
        }
#pragma unroll
        for (int k = 0; k < BK; ++k) {
            const float4 a0 = *(const float4*)&As[k][ty << 2];
            const float4 a1 = *(const float4*)&As[k][64 + (ty << 2)];
            const float4 b0 = *(const float4*)&Bs[k][tx << 2];
            const float a0v[4] = {a0.x, a0.y, a0.z, a0.w};
            const float a1v[4] = {a1.x, a1.y, a1.z, a1.w};
            const float bv[4]  = {b0.x, b0.y, b0.z, b0.w};
#pragma unroll
            for (int i = 0; i < 4; ++i)
#pragma unroll
                for (int j = 0; j < 4; ++j) {
                    acc[0][i][j] = fmaf(a0v[i], bv[j], acc[0][i][j]);
                    acc[1][i][j] = fmaf(a1v[i], bv[j], acc[1][i][j]);
                }
        }
        if (more) {
            __syncthreads();
#pragma unroll
            for (int q = 0; q < 4; ++q) {
                As[(cc << 2) + q][rr]      = ((const float*)&va0)[q];
                As[(cc << 2) + q][rr + 64] = ((const float*)&va1)[q];
                Bs[(cc << 2) + q][rr]      = ((const float*)&vb0)[q];
            }
            __syncthreads();
        }
    }

    float c[TQ_KC];
#pragma unroll
    for (int q = 0; q < TQ_KC; ++q) c[q] = Cent[q];

#pragma unroll
    for (int r = 0; r < 2; ++r)
#pragma unroll
        for (int i = 0; i < 4; ++i) {
            const int m = m0 + (r << 6) + (ty << 2) + i;
            float o[4];
#pragma unroll
            for (int j = 0; j < 4; ++j) {
                // y = S1 (from LDS) + S2 — single f32 add, exact R9 semantics
                const float y = ylds[(r << 4) + (i << 2) + j][tid] + acc[r][i][j];
                int best = 0;
                float bd = fabsf(y - c[0]);
#pragma unroll
                for (int q = 1; q < TQ_KC; ++q) {
                    const float d = fabsf(y - c[q]);
                    if (d < bd) { bd = d; best = q; }
                }
                o[j] = (float)best;
            }
            *(float4*)(OutIdx + (size_t)m * TQ_D + n0 + (tx << 2)) =
                make_float4(o[0], o[1], o[2], o[3]);
        }
}

// ---------------------------------------------------------------------------
// Kernel 2: x_hat = dequant(idx) @ Pi (NN GEMM, f32) — UNCHANGED from R10
// (measured ~53us, at the f32 vector-FMA roofline).
// ---------------------------------------------------------------------------
__global__ __launch_bounds__(256, 2)
void tq_dequant_unrotate(const float* __restrict__ IdxF,
                         const float* __restrict__ Pi,
                         const float* __restrict__ Cent,
                         float* __restrict__ Xhat)
{
    __shared__ float As[BK][LDA];
    __shared__ float Bs[BK][LDB];
    __shared__ float cs[TQ_KC];

    const int tid = threadIdx.x;
    const int m0 = blockIdx.y * BM;
    const int n0 = blockIdx.x * BN;
    const int tx = tid & 15;
    const int ty = tid >> 4;

    const int rr = tid >> 2;
    const int cc = tid & 3;
    const int kr = tid >> 4;
    const int cq = tid & 15;

    const float* aPtr = IdxF + (size_t)(m0 + rr) * TQ_D + (cc << 2);
    const float* pPtr = Pi + (size_t)kr * TQ_D + n0 + (cq << 2);

    if (tid < TQ_KC) cs[tid] = Cent[tid];

    float acc[2][4][4];
#pragma unroll
    for (int r = 0; r < 2; ++r)
#pragma unroll
        for (int i = 0; i < 4; ++i)
#pragma unroll
            for (int j = 0; j < 4; ++j) acc[r][i][j] = 0.0f;

    float4 va0 = *(const float4*)(aPtr);
    float4 va1 = *(const float4*)(aPtr + (size_t)64 * TQ_D);
    float4 vb0 = *(const float4*)(pPtr);
    __syncthreads();   // cs[] ready
#pragma unroll
    for (int q = 0; q < 4; ++q) {
        As[(cc << 2) + q][rr]      = cs[((int)((const float*)&va0)[q]) & 15];
        As[(cc << 2) + q][rr + 64] = cs[((int)((const float*)&va1)[q]) & 15];
    }
    *(float4*)&Bs[kr][cq << 2] = vb0;
    __syncthreads();

    for (int kt = 0; kt < NTILES; ++kt) {
        const bool more = (kt + 1) < NTILES;
        if (more) {
            const float* ap = aPtr + (kt + 1) * BK;
            const float* bp = pPtr + (size_t)(kt + 1) * BK * TQ_D;
            va0 = *(const float4*)(ap);
            va1 = *(const float4*)(ap + (size_t)64 * TQ_D);
            vb0 = *(const float4*)(bp);
        }
#pragma unroll
        for (int k = 0; k < BK; ++k) {
            const float4 a0 = *(const float4*)&As[k][ty << 2];
            const float4 a1 = *(const float4*)&As[k][64 + (ty << 2)];
            const float4 b0 = *(const float4*)&Bs[k][tx << 2];
            const float a0v[4] = {a0.x, a0.y, a0.z, a0.w};
            const float a1v[4] = {a1.x, a1.y, a1.z, a1.w};
            const float bv[4]  = {b0.x, b0.y, b0.z, b0.w};
#pragma unroll
            for (int i = 0; i < 4; ++i)
#pragma unroll
                for (int j = 0; j < 4; ++j) {
                    acc[0][i][j] = fmaf(a0v[i], bv[j], acc[0][i][j]);
                    acc[1][i][j] = fmaf(a1v[i], bv[j], acc[1][i][j]);
                }
        }
        if (more) {
            __syncthreads();
#pragma unroll
            for (int q = 0; q < 4; ++q) {
                As[(cc << 2) + q][rr]      = cs[((int)((const float*)&va0)[q]) & 15];
                As[(cc << 2) + q][rr + 64] = cs[((int)((const float*)&va1)[q]) & 15];
            }
            *(float4*)&Bs[kr][cq << 2] = vb0;
            __syncthreads();
        }
    }

#pragma unroll
    for (int r = 0; r < 2; ++r)
#pragma unroll
        for (int i = 0; i < 4; ++i) {
            const int m = m0 + (r << 6) + (ty << 2) + i;
            *(float4*)(Xhat + (size_t)m * TQ_D + n0 + (tx << 2)) =
                make_float4(acc[r][i][0], acc[r][i][1], acc[r][i][2], acc[r][i][3]);
        }
}

// ---------------------------------------------------------------------------
extern "C" void kernel_launch(void* const* d_in, const int* in_sizes, int n_in,
                              void* d_out, int out_size, void* d_ws, size_t ws_size,
                              hipStream_t stream)
{
    const float* x    = (const float*)d_in[0];   // [N, 1024]
    const float* Pi   = (const float*)d_in[1];   // [1024, 1024]
    const float* cent = (const float*)d_in[2];   // [16]
    float* out = (float*)d_out;

    const int ND = in_sizes[0];      // N * 1024
    const int N  = ND / TQ_D;        // 4096

    float* xhat = out;               // output 0: [N,1024] f32
    float* oidx = out + ND;          // output 1: indices as float

    dim3 grid(TQ_D / BN, N / BM);    // (16, 32) = 512 blocks
    tq_rotate_quant<<<grid, 256, 0, stream>>>(x, Pi, cent, oidx);
    tq_dequant_unrotate<<<grid, 256, 0, stream>>>(oidx, Pi, cent, xhat);
}